// Round 20
// baseline (1611.834 us; speedup 1.0000x reference)
//
#include <hip/hip_runtime.h>
#include <hip/hip_bf16.h>

#define NB 512
#define NL 128
#define NF 900
#define ND 512
#define NE 8

typedef short bf16x8 __attribute__((ext_vector_type(8)));
typedef float f32x4 __attribute__((ext_vector_type(4)));

// Output encoding (measured R5-R18, R18 PASSED): harness reads d_out as u32
// slots, bf16 payload in HIGH u16. RNE-round and shift.
__device__ __forceinline__ unsigned int enc_bf16_hi(float v) {
    unsigned int u = __float_as_uint(v);
    return (u + 0x7FFFu + ((u >> 16) & 1u)) & 0xFFFF0000u;
}
__device__ __forceinline__ unsigned short bf16r(float v) {
    unsigned int u = __float_as_uint(v);
    return (unsigned short)((u + 0x7FFFu + ((u >> 16) & 1u)) >> 16);
}
__device__ __forceinline__ float b2f(unsigned short h) {
    return __uint_as_float(((unsigned int)h) << 16);
}
// split v into hi (bf16) + lo (bf16 of residual); |v - hi - lo| <= 2^-16 |v|
__device__ __forceinline__ void split2(float v, unsigned short& hi, unsigned short& lo) {
    hi = bf16r(v);
    lo = bf16r(v - b2f(hi));
}

// ---------------- H0 gates (verified R18) ----------------
__global__ void gates_kernel(const float* __restrict__ logits,
                             const int* __restrict__ masks,
                             int* __restrict__ eidx,
                             float* __restrict__ gval) {
    int b = blockIdx.x * blockDim.x + threadIdx.x;
    if (b >= NB) return;
    float l[NE], pr[NE], pm[NE];
    int mk[NE];
    float mx = -3.0e38f;
    for (int e = 0; e < NE; ++e) {
        l[e] = logits[b * NE + e];
        mk[e] = masks[b * NE + e];
        mx = fmaxf(mx, l[e]);
    }
    float Z = 0.f;
    for (int e = 0; e < NE; ++e) { pr[e] = expf(l[e] - mx); Z += pr[e]; }
    for (int e = 0; e < NE; ++e) { pr[e] /= Z; pm[e] = (mk[e] == 1) ? pr[e] : 0.f; }
    int i1 = 0;
    for (int e = 1; e < NE; ++e) if (pm[e] > pm[i1]) i1 = e;
    int i2 = (i1 == 0) ? 1 : 0;
    for (int e = 0; e < NE; ++e) if (e != i1 && pm[e] > pm[i2]) i2 = e;
    float v1 = pm[i1], v2 = pm[i2];
    float den = v1 + v2 + 1e-9f;
    eidx[2 * b] = i1; eidx[2 * b + 1] = i2;
    gval[2 * b] = v1 / den; gval[2 * b + 1] = v2 / den;
}

// ---------------- split-precision MFMA GEMM ----------------
// 256 thr = 4 waves (2x2), 128 rows x 128 cols per block, K-step 32.
// x = xh + xl, W = wh + wl (bf16 pairs). acc += xh*wh + xh*wl + xl*wh.
__global__ __launch_bounds__(256)
void moe_mfma_kernel(const float* __restrict__ x,
                     const float* __restrict__ W,
                     const float* __restrict__ bias,
                     const int* __restrict__ eidx,
                     const float* __restrict__ gval,
                     unsigned int* __restrict__ out32) {
    __shared__ unsigned short xh[128 * 40], xl[128 * 40];
    __shared__ unsigned short wh[128 * 40], wl[128 * 40];

    const int b    = blockIdx.y;
    const int n0   = blockIdx.x * 128;
    const int t    = threadIdx.x;
    const int lane = t & 63;
    const int wid  = t >> 6;
    const int wr   = wid >> 1, wc = wid & 1;

    const int   e0 = eidx[2 * b], e1 = eidx[2 * b + 1];
    const float g0 = gval[2 * b], g1 = gval[2 * b + 1];

    const float* xb = x + (size_t)b * NL * NF;
    const float* W0 = W + (size_t)e0 * NF * ND + n0;
    const float* W1 = W + (size_t)e1 * NF * ND + n0;

    f32x4 acc[4][4] = {};

    for (int k0 = 0; k0 < 928; k0 += 32) {   // 29 steps, tail zero-padded
        // ---- stage x: 128 rows x 32 k, hi+lo ----
#pragma unroll
        for (int p = 0; p < 4; ++p) {
            int idx = t + 256 * p;
            int row = idx >> 3, c4 = idx & 7;
            int f = k0 + 4 * c4;
            float v0, v1, v2, v3;
            if (f + 3 < NF) {
                float4 v = *(const float4*)(xb + (size_t)row * NF + f);
                v0 = v.x; v1 = v.y; v2 = v.z; v3 = v.w;
            } else {
                v0 = (f     < NF) ? xb[(size_t)row * NF + f    ] : 0.f;
                v1 = (f + 1 < NF) ? xb[(size_t)row * NF + f + 1] : 0.f;
                v2 = (f + 2 < NF) ? xb[(size_t)row * NF + f + 2] : 0.f;
                v3 = (f + 3 < NF) ? xb[(size_t)row * NF + f + 3] : 0.f;
            }
            ushort4 h, lo;
            split2(v0, h.x, lo.x); split2(v1, h.y, lo.y);
            split2(v2, h.z, lo.z); split2(v3, h.w, lo.w);
            *(ushort4*)&xh[row * 40 + 4 * c4] = h;
            *(ushort4*)&xl[row * 40 + 4 * c4] = lo;
        }
        // ---- stage W blended + transposed: [col][k], hi+lo, k-pair u32 ----
#pragma unroll
        for (int p = 0; p < 8; ++p) {
            int idx = t + 256 * p;
            int c = idx & 127, kp = idx >> 7;   // kp 0..15
            int f = k0 + 2 * kp;
            float u0 = 0.f, u1 = 0.f;
            if (f < NF)     u0 = g0 * W0[(size_t)f * ND + c]       + g1 * W1[(size_t)f * ND + c];
            if (f + 1 < NF) u1 = g0 * W0[(size_t)(f + 1) * ND + c] + g1 * W1[(size_t)(f + 1) * ND + c];
            unsigned short h0, l0, h1, l1;
            split2(u0, h0, l0); split2(u1, h1, l1);
            *(unsigned int*)&wh[c * 40 + 2 * kp] = (unsigned int)h0 | ((unsigned int)h1 << 16);
            *(unsigned int*)&wl[c * 40 + 2 * kp] = (unsigned int)l0 | ((unsigned int)l1 << 16);
        }
        __syncthreads();

        // ---- fragments + 3x MFMA ----
        bf16x8 ah[4], al[4], bh[4], bl[4];
#pragma unroll
        for (int fm = 0; fm < 4; ++fm) {
            int off = (wr * 64 + fm * 16 + (lane & 15)) * 40 + (lane >> 4) * 8;
            ah[fm] = *(const bf16x8*)&xh[off];
            al[fm] = *(const bf16x8*)&xl[off];
        }
#pragma unroll
        for (int fn = 0; fn < 4; ++fn) {
            int off = (wc * 64 + fn * 16 + (lane & 15)) * 40 + (lane >> 4) * 8;
            bh[fn] = *(const bf16x8*)&wh[off];
            bl[fn] = *(const bf16x8*)&wl[off];
        }
#pragma unroll
        for (int fm = 0; fm < 4; ++fm)
#pragma unroll
            for (int fn = 0; fn < 4; ++fn) {
                acc[fm][fn] = __builtin_amdgcn_mfma_f32_16x16x32_bf16(ah[fm], bh[fn], acc[fm][fn], 0, 0, 0);
                acc[fm][fn] = __builtin_amdgcn_mfma_f32_16x16x32_bf16(ah[fm], bl[fn], acc[fm][fn], 0, 0, 0);
                acc[fm][fn] = __builtin_amdgcn_mfma_f32_16x16x32_bf16(al[fm], bh[fn], acc[fm][fn], 0, 0, 0);
            }
        __syncthreads();
    }

    // ---- epilogue: bias + high-u16 bf16 stores (C/D: col=lane&15, row=(lane>>4)*4+j) ----
#pragma unroll
    for (int fn = 0; fn < 4; ++fn) {
        int col = n0 + wc * 64 + fn * 16 + (lane & 15);
        float bc = g0 * bias[e0 * ND + col] + g1 * bias[e1 * ND + col];
#pragma unroll
        for (int fm = 0; fm < 4; ++fm) {
            int rbase = wr * 64 + fm * 16 + (lane >> 4) * 4;
#pragma unroll
            for (int j = 0; j < 4; ++j) {
                float v = acc[fm][fn][j] + bc;
                out32[((size_t)b * NL + rbase + j) * ND + col] = enc_bf16_hi(v);
            }
        }
    }
}

extern "C" void kernel_launch(void* const* d_in, const int* in_sizes, int n_in,
                              void* d_out, int out_size, void* d_ws, size_t ws_size,
                              hipStream_t stream) {
    const float* x      = (const float*)d_in[0];   // [B, L, 900] f32
    const float* logits = (const float*)d_in[1];   // [B, 8] f32
    const int*   masks  = (const int*)d_in[2];     // [B, 8] i32
    const float* W      = (const float*)d_in[3];   // [8, 900, 512] f32
    const float* bias   = (const float*)d_in[4];   // [8, 512] f32
    unsigned int* out32 = (unsigned int*)d_out;    // u32 slots, bf16 in high u16

    int*   eidx = (int*)d_ws;
    float* gval = (float*)((char*)d_ws + 4096);

    gates_kernel<<<dim3(2), dim3(256), 0, stream>>>(logits, masks, eidx, gval);
    moe_mfma_kernel<<<dim3(ND / 128, NB), dim3(256), 0, stream>>>(
        x, W, bias, eidx, gval, out32);
}

// Round 21
// 487.095 us; speedup vs baseline: 3.3091x; 3.3091x over previous
//
#include <hip/hip_runtime.h>
#include <hip/hip_bf16.h>

#define NB 512
#define NL 128
#define NF 900
#define ND 512
#define NE 8
#define LSTR 36                      // LDS row stride (ushorts): 32 data + 4 pad
#define WT_OFF 8192
#define WT_BYTES ((size_t)NE * ND * NF * 4)

typedef short bf16x8 __attribute__((ext_vector_type(8)));
typedef float f32x4 __attribute__((ext_vector_type(4)));

// Output encoding (measured R5-R18; R18/R20 PASSED): harness reads d_out as
// u32 slots, bf16 payload in HIGH u16.
static __device__ __forceinline__ unsigned int enc_bf16_hi(float v) {
    unsigned int u = __float_as_uint(v);
    return (u + 0x7FFFu + ((u >> 16) & 1u)) & 0xFFFF0000u;
}
static __device__ __forceinline__ unsigned short bf16r(float v) {
    unsigned int u = __float_as_uint(v);
    return (unsigned short)((u + 0x7FFFu + ((u >> 16) & 1u)) >> 16);
}
static __device__ __forceinline__ float b2f(unsigned short h) {
    return __uint_as_float(((unsigned int)h) << 16);
}
static __device__ __forceinline__ void split2(float v, unsigned short& hi, unsigned short& lo) {
    hi = bf16r(v); lo = bf16r(v - b2f(hi));
}
static __device__ __forceinline__ bf16x8 read8(const unsigned short* p) {
    union { ushort4 u[2]; bf16x8 v; } r;
    r.u[0] = *(const ushort4*)(p);        // 8B-aligned (LSTR even, offsets even)
    r.u[1] = *(const ushort4*)(p + 4);
    return r.v;
}

// ---------------- H0 gates (verified R18/R20) ----------------
__global__ void gates_kernel(const float* __restrict__ logits,
                             const int* __restrict__ masks,
                             int* __restrict__ eidx,
                             float* __restrict__ gval) {
    int b = blockIdx.x * blockDim.x + threadIdx.x;
    if (b >= NB) return;
    float l[NE], pr[NE], pm[NE];
    int mk[NE];
    float mx = -3.0e38f;
    for (int e = 0; e < NE; ++e) {
        l[e] = logits[b * NE + e];
        mk[e] = masks[b * NE + e];
        mx = fmaxf(mx, l[e]);
    }
    float Z = 0.f;
    for (int e = 0; e < NE; ++e) { pr[e] = expf(l[e] - mx); Z += pr[e]; }
    for (int e = 0; e < NE; ++e) { pr[e] /= Z; pm[e] = (mk[e] == 1) ? pr[e] : 0.f; }
    int i1 = 0;
    for (int e = 1; e < NE; ++e) if (pm[e] > pm[i1]) i1 = e;
    int i2 = (i1 == 0) ? 1 : 0;
    for (int e = 0; e < NE; ++e) if (e != i1 && pm[e] > pm[i2]) i2 = e;
    float v1 = pm[i1], v2 = pm[i2];
    float den = v1 + v2 + 1e-9f;
    eidx[2 * b] = i1; eidx[2 * b + 1] = i2;
    gval[2 * b] = v1 / den; gval[2 * b + 1] = v2 / den;
}

// ---------------- W transpose: Wt[e][d][f] = W[e][f][d] ----------------
__global__ void wt_kernel(const float* __restrict__ W, float* __restrict__ Wt) {
    __shared__ float tile[32][33];
    const int e = blockIdx.z, f0 = blockIdx.x * 32, d0 = blockIdx.y * 32;
    const int tx = threadIdx.x & 31, ty = threadIdx.x >> 5;   // 32 x 8
    const float* Wb = W + (size_t)e * NF * ND;
    float* Tb = Wt + (size_t)e * ND * NF;
#pragma unroll
    for (int i = 0; i < 4; ++i) {
        int f = f0 + ty + 8 * i;
        tile[ty + 8 * i][tx] = (f < NF) ? Wb[(size_t)f * ND + d0 + tx] : 0.f;
    }
    __syncthreads();
#pragma unroll
    for (int i = 0; i < 4; ++i) {
        int d = d0 + ty + 8 * i, f = f0 + tx;
        if (f < NF) Tb[(size_t)d * NF + f] = tile[tx][ty + 8 * i];
    }
}

// ---------------- split-precision MFMA GEMM, dbuf, low-reg ----------------
__global__ __launch_bounds__(256, 2)
void moe_mfma2_kernel(const float* __restrict__ x,
                      const float* __restrict__ Wt,
                      const float* __restrict__ bias,
                      const int* __restrict__ eidx,
                      const float* __restrict__ gval,
                      unsigned int* __restrict__ out32) {
    __shared__ unsigned short sxh[2][128 * LSTR], sxl[2][128 * LSTR];
    __shared__ unsigned short swh[2][128 * LSTR], swl[2][128 * LSTR];

    const int b = blockIdx.y, n0 = blockIdx.x * 128;
    const int t = threadIdx.x, lane = t & 63, wid = t >> 6;
    const int wr = wid >> 1, wc = wid & 1;

    const int e0 = eidx[2 * b], e1 = eidx[2 * b + 1];
    const float g0 = gval[2 * b], g1 = gval[2 * b + 1];

    const float* xb = x + (size_t)b * NL * NF;
    const float* T0 = Wt + (size_t)e0 * ND * NF + (size_t)n0 * NF;
    const float* T1 = Wt + (size_t)e1 * ND * NF + (size_t)n0 * NF;

    const int rowi = t >> 3;     // 0..31 (+32 per p)
    const int k4   = t & 7;

    f32x4 acc[4][4] = {};

    // prologue: stage step 0 into buf 0 (k0=0, all f valid)
#pragma unroll
    for (int p = 0; p < 4; ++p) {
        int row = rowi + 32 * p;
        int f = 4 * k4;
        float4 xv = *(const float4*)(xb + (size_t)row * NF + f);
        float4 w0 = *(const float4*)(T0 + (size_t)row * NF + f);
        float4 w1 = *(const float4*)(T1 + (size_t)row * NF + f);
        ushort4 xh, xl, wh, wl;
        split2(xv.x, xh.x, xl.x); split2(xv.y, xh.y, xl.y);
        split2(xv.z, xh.z, xl.z); split2(xv.w, xh.w, xl.w);
        float c0 = g0 * w0.x + g1 * w1.x, c1 = g0 * w0.y + g1 * w1.y;
        float c2 = g0 * w0.z + g1 * w1.z, c3 = g0 * w0.w + g1 * w1.w;
        split2(c0, wh.x, wl.x); split2(c1, wh.y, wl.y);
        split2(c2, wh.z, wl.z); split2(c3, wh.w, wl.w);
        int o = row * LSTR + 4 * k4;
        *(ushort4*)&sxh[0][o] = xh; *(ushort4*)&sxl[0][o] = xl;
        *(ushort4*)&swh[0][o] = wh; *(ushort4*)&swl[0][o] = wl;
    }

    int cur = 0;
    for (int step = 0; step < 29; ++step) {
        __syncthreads();
        // issue next-step global loads early (latency hides under MFMA phase)
        float4 nx[4], nw0[4], nw1[4];
        const int k0n = (step + 1) * 32;
        if (step < 28) {
#pragma unroll
            for (int p = 0; p < 4; ++p) {
                int row = rowi + 32 * p;
                int f = k0n + 4 * k4;
                float4 z; z.x = z.y = z.z = z.w = 0.f;
                bool ok = (f < NF);   // NF%4==0: chunks are fully in or out
                nx[p]  = ok ? *(const float4*)(xb + (size_t)row * NF + f) : z;
                nw0[p] = ok ? *(const float4*)(T0 + (size_t)row * NF + f) : z;
                nw1[p] = ok ? *(const float4*)(T1 + (size_t)row * NF + f) : z;
            }
        }
        // fragments + 3x MFMA on cur
        bf16x8 ah[4], al[4], bh[4], bl[4];
#pragma unroll
        for (int fm = 0; fm < 4; ++fm) {
            int o = (wr * 64 + fm * 16 + (lane & 15)) * LSTR + (lane >> 4) * 8;
            ah[fm] = read8(&sxh[cur][o]); al[fm] = read8(&sxl[cur][o]);
        }
#pragma unroll
        for (int fn = 0; fn < 4; ++fn) {
            int o = (wc * 64 + fn * 16 + (lane & 15)) * LSTR + (lane >> 4) * 8;
            bh[fn] = read8(&swh[cur][o]); bl[fn] = read8(&swl[cur][o]);
        }
#pragma unroll
        for (int fm = 0; fm < 4; ++fm)
#pragma unroll
            for (int fn = 0; fn < 4; ++fn) {
                acc[fm][fn] = __builtin_amdgcn_mfma_f32_16x16x32_bf16(ah[fm], bh[fn], acc[fm][fn], 0, 0, 0);
                acc[fm][fn] = __builtin_amdgcn_mfma_f32_16x16x32_bf16(ah[fm], bl[fn], acc[fm][fn], 0, 0, 0);
                acc[fm][fn] = __builtin_amdgcn_mfma_f32_16x16x32_bf16(al[fm], bh[fn], acc[fm][fn], 0, 0, 0);
            }
        // split + write next buffer (no barrier needed: disjoint buffer)
        if (step < 28) {
            int nxt = cur ^ 1;
#pragma unroll
            for (int p = 0; p < 4; ++p) {
                int row = rowi + 32 * p;
                ushort4 xh, xl, wh, wl;
                split2(nx[p].x, xh.x, xl.x); split2(nx[p].y, xh.y, xl.y);
                split2(nx[p].z, xh.z, xl.z); split2(nx[p].w, xh.w, xl.w);
                float c0 = g0 * nw0[p].x + g1 * nw1[p].x, c1 = g0 * nw0[p].y + g1 * nw1[p].y;
                float c2 = g0 * nw0[p].z + g1 * nw1[p].z, c3 = g0 * nw0[p].w + g1 * nw1[p].w;
                split2(c0, wh.x, wl.x); split2(c1, wh.y, wl.y);
                split2(c2, wh.z, wl.z); split2(c3, wh.w, wl.w);
                int o = row * LSTR + 4 * k4;
                *(ushort4*)&sxh[nxt][o] = xh; *(ushort4*)&sxl[nxt][o] = xl;
                *(ushort4*)&swh[nxt][o] = wh; *(ushort4*)&swl[nxt][o] = wl;
            }
            cur = nxt;
        }
    }

    // epilogue (layout verified R18/R20): D col=lane&15 (n), row=(lane>>4)*4+j (m)
#pragma unroll
    for (int fn = 0; fn < 4; ++fn) {
        int col = n0 + wc * 64 + fn * 16 + (lane & 15);
        float bc = g0 * bias[e0 * ND + col] + g1 * bias[e1 * ND + col];
#pragma unroll
        for (int fm = 0; fm < 4; ++fm) {
            int rbase = wr * 64 + fm * 16 + (lane >> 4) * 4;
#pragma unroll
            for (int j = 0; j < 4; ++j)
                out32[((size_t)b * NL + rbase + j) * ND + col] = enc_bf16_hi(acc[fm][fn][j] + bc);
        }
    }
}

// ---------------- fallback (R20 kernel, passed 1612us) for small ws ----------------
__global__ __launch_bounds__(256)
void moe_mfma_fb_kernel(const float* __restrict__ x, const float* __restrict__ W,
                        const float* __restrict__ bias, const int* __restrict__ eidx,
                        const float* __restrict__ gval, unsigned int* __restrict__ out32) {
    __shared__ unsigned short xh[128 * 40], xl[128 * 40];
    __shared__ unsigned short wh[128 * 40], wl[128 * 40];
    const int b = blockIdx.y, n0 = blockIdx.x * 128;
    const int t = threadIdx.x, lane = t & 63, wid = t >> 6;
    const int wr = wid >> 1, wc = wid & 1;
    const int e0 = eidx[2 * b], e1 = eidx[2 * b + 1];
    const float g0 = gval[2 * b], g1 = gval[2 * b + 1];
    const float* xb = x + (size_t)b * NL * NF;
    const float* W0 = W + (size_t)e0 * NF * ND + n0;
    const float* W1 = W + (size_t)e1 * NF * ND + n0;
    f32x4 acc[4][4] = {};
    for (int k0 = 0; k0 < 928; k0 += 32) {
#pragma unroll
        for (int p = 0; p < 4; ++p) {
            int idx = t + 256 * p, row = idx >> 3, c4 = idx & 7, f = k0 + 4 * c4;
            float4 v; v.x = v.y = v.z = v.w = 0.f;
            if (f + 3 < NF) v = *(const float4*)(xb + (size_t)row * NF + f);
            ushort4 h, lo;
            split2(v.x, h.x, lo.x); split2(v.y, h.y, lo.y);
            split2(v.z, h.z, lo.z); split2(v.w, h.w, lo.w);
            *(ushort4*)&xh[row * 40 + 4 * c4] = h; *(ushort4*)&xl[row * 40 + 4 * c4] = lo;
        }
#pragma unroll
        for (int p = 0; p < 8; ++p) {
            int idx = t + 256 * p, c = idx & 127, kp = idx >> 7, f = k0 + 2 * kp;
            float u0 = 0.f, u1 = 0.f;
            if (f < NF)     u0 = g0 * W0[(size_t)f * ND + c] + g1 * W1[(size_t)f * ND + c];
            if (f + 1 < NF) u1 = g0 * W0[(size_t)(f + 1) * ND + c] + g1 * W1[(size_t)(f + 1) * ND + c];
            unsigned short h0, l0, h1, l1;
            split2(u0, h0, l0); split2(u1, h1, l1);
            *(unsigned int*)&wh[c * 40 + 2 * kp] = (unsigned int)h0 | ((unsigned int)h1 << 16);
            *(unsigned int*)&wl[c * 40 + 2 * kp] = (unsigned int)l0 | ((unsigned int)l1 << 16);
        }
        __syncthreads();
        bf16x8 ah[4], al[4], bh[4], bl[4];
#pragma unroll
        for (int fm = 0; fm < 4; ++fm) {
            int off = (wr * 64 + fm * 16 + (lane & 15)) * 40 + (lane >> 4) * 8;
            ah[fm] = *(const bf16x8*)&xh[off]; al[fm] = *(const bf16x8*)&xl[off];
        }
#pragma unroll
        for (int fn = 0; fn < 4; ++fn) {
            int off = (wc * 64 + fn * 16 + (lane & 15)) * 40 + (lane >> 4) * 8;
            bh[fn] = *(const bf16x8*)&wh[off]; bl[fn] = *(const bf16x8*)&wl[off];
        }
#pragma unroll
        for (int fm = 0; fm < 4; ++fm)
#pragma unroll
            for (int fn = 0; fn < 4; ++fn) {
                acc[fm][fn] = __builtin_amdgcn_mfma_f32_16x16x32_bf16(ah[fm], bh[fn], acc[fm][fn], 0, 0, 0);
                acc[fm][fn] = __builtin_amdgcn_mfma_f32_16x16x32_bf16(ah[fm], bl[fn], acc[fm][fn], 0, 0, 0);
                acc[fm][fn] = __builtin_amdgcn_mfma_f32_16x16x32_bf16(al[fm], bh[fn], acc[fm][fn], 0, 0, 0);
            }
        __syncthreads();
    }
#pragma unroll
    for (int fn = 0; fn < 4; ++fn) {
        int col = n0 + wc * 64 + fn * 16 + (lane & 15);
        float bc = g0 * bias[e0 * ND + col] + g1 * bias[e1 * ND + col];
#pragma unroll
        for (int fm = 0; fm < 4; ++fm) {
            int rbase = wr * 64 + fm * 16 + (lane >> 4) * 4;
#pragma unroll
            for (int j = 0; j < 4; ++j)
                out32[((size_t)b * NL + rbase + j) * ND + col] = enc_bf16_hi(acc[fm][fn][j] + bc);
        }
    }
}

extern "C" void kernel_launch(void* const* d_in, const int* in_sizes, int n_in,
                              void* d_out, int out_size, void* d_ws, size_t ws_size,
                              hipStream_t stream) {
    const float* x      = (const float*)d_in[0];
    const float* logits = (const float*)d_in[1];
    const int*   masks  = (const int*)d_in[2];
    const float* W      = (const float*)d_in[3];
    const float* bias   = (const float*)d_in[4];
    unsigned int* out32 = (unsigned int*)d_out;

    int*   eidx = (int*)d_ws;
    float* gval = (float*)((char*)d_ws + 4096);

    gates_kernel<<<dim3(2), dim3(256), 0, stream>>>(logits, masks, eidx, gval);

    if (ws_size >= WT_OFF + WT_BYTES) {
        float* Wt = (float*)((char*)d_ws + WT_OFF);
        wt_kernel<<<dim3(29, 16, 8), dim3(256), 0, stream>>>(W, Wt);
        moe_mfma2_kernel<<<dim3(ND / 128, NB), dim3(256), 0, stream>>>(
            x, Wt, bias, eidx, gval, out32);
    } else {
        moe_mfma_fb_kernel<<<dim3(ND / 128, NB), dim3(256), 0, stream>>>(
            x, W, bias, eidx, gval, out32);
    }
}